// Round 7
// baseline (98.632 us; speedup 1.0000x reference)
//
#include <hip/hip_runtime.h>

// Fused two-sided GraphSage-style embed + linear + dot. Single kernel.
// B=16384, MAX_DEG=50, D=64. Block = 512 threads (8 waves), EPB=16 elems,
// grid = 1024 (4 blocks/CU, 32 waves/CU).
// Phase 0: in-kernel mask-layout detection (wave 0, ballots).
// Phase 1: lane = embedding dim. Metadata for both elems -> SoA compaction
//          (idx,w) into LDS -> explicit two-bank ping-pong gather pipeline:
//          2 banks x 16 scalar row-loads, ~32 loads outstanding, each FMA
//          bank waits only on its own 16 (counted-vmcnt pattern).
// Phase 2: mat-vec mini-GEMM, wave = (side, 4 elems), W amortized, unroll 2.
// Phase 3: select + dot + wave reduce.

constexpr int KDEG  = 50;
constexpr int DIM   = 64;
constexpr int SLOTS = 56;             // KDEG padded to multiple of 8
constexpr int EPB   = 16;             // elements per block

template <typename MT>
__device__ __forceinline__ void load_meta(const void* __restrict__ mask_p,
                                          const float* __restrict__ sel,
                                          const int* __restrict__ neibs,
                                          int base, int lane,
                                          int& idx, float& w, bool& act) {
  if (lane < KDEG) {
    MT m    = ((const MT*)mask_p)[base + lane];
    float s = sel[base + lane];
    idx     = neibs[base + lane];
    act     = (m != (MT)0);
    w       = act ? s : 0.0f;
  } else { idx = 0; w = 0.0f; act = false; }
}

// Compact active (idx,w) into slots [0,cnt); fill [cnt,SLOTS) with zeros. SoA.
__device__ __forceinline__ int compact_side(int lane, int idx, float w, bool act,
                                            int* __restrict__ sidx,
                                            float* __restrict__ sw) {
  unsigned long long balA = __ballot(act);
  unsigned long long balI = __ballot(!act && (lane < SLOTS));
  int cnt = __popcll(balA);
  unsigned long long below = (1ULL << lane) - 1ULL;
  int pos = act ? __popcll(balA & below)
                : cnt + __popcll(balI & below);
  if (lane < SLOTS) {
    sidx[pos] = act ? idx : 0;
    sw[pos]   = act ? w   : 0.0f;
  }
  return cnt;
}

__global__ __launch_bounds__(512, 8) void fused_graphsage_dot(
    const int* __restrict__ nodes_u, const int* __restrict__ nodes_v,
    const int* __restrict__ u_neibs, const int* __restrict__ v_neibs,
    const void* __restrict__ u_mask_p, const void* __restrict__ v_mask_p,
    const float* __restrict__ u_sel, const float* __restrict__ v_sel,
    const float* __restrict__ u2e, const float* __restrict__ v2e,
    const float* __restrict__ Wu, const float* __restrict__ bu,
    const float* __restrict__ Wv, const float* __restrict__ bv,
    float* __restrict__ out)
{
  __shared__ float sx  [EPB][256];      // [self_u|agg_u|self_v|agg_v] per elem
  __shared__ float slin[2][EPB][DIM];   // mat-vec results per side
  __shared__ int   sidx[EPB][2][SLOTS];
  __shared__ float swt [EPB][2][SLOTS];
  __shared__ int   slay;

  const int lane = threadIdx.x & 63;    // = embedding dim in phase 1
  const int wvid = threadIdx.x >> 6;    // 0..7
  const int eb0  = blockIdx.x * EPB;
  const int e0   = wvid * 2, e1 = e0 + 1;
  const int g0   = eb0 + e0, g1 = eb0 + e1;
  const int b0   = g0 * KDEG, b1 = g1 * KDEG;

  // self-embedding loads issued first (independent of everything below)
  float self_u0 = u2e[(size_t)nodes_u[g0] * DIM + lane];
  float self_v0 = v2e[(size_t)nodes_v[g0] * DIM + lane];
  float self_u1 = u2e[(size_t)nodes_u[g1] * DIM + lane];
  float self_v1 = v2e[(size_t)nodes_v[g1] * DIM + lane];

  // ---- Phase 0: mask storage layout detection (bool dtype ambiguity) ------
  // lay 0: int32 0/1   lay 1: uint8 0/1   lay 2: float32 0.0/1.0
  if (wvid == 0) {
    uchar4 b4 = ((const uchar4*)u_mask_p)[lane];   // first 256 bytes
    bool gt1  = (b4.x > 1) | (b4.y > 1) | (b4.z > 1) | (b4.w > 1);
    bool offw = ((b4.y | b4.z | b4.w) != 0);
    unsigned long long bg = __ballot(gt1);
    unsigned long long bo = __ballot(offw);
    if (lane == 0) slay = bg ? 2 : (bo ? 1 : 0);
  }
  __syncthreads();
  const int lay = slay;

  // ---- Phase 1a: metadata for BOTH elements, then SoA compaction -----------
  int iu0, iv0, iu1, iv1; float wu0, wv0, wu1, wv1; bool au0_, av0_, au1_, av1_;
  if (lay == 0) {
    load_meta<int>(u_mask_p, u_sel, u_neibs, b0, lane, iu0, wu0, au0_);
    load_meta<int>(v_mask_p, v_sel, v_neibs, b0, lane, iv0, wv0, av0_);
    load_meta<int>(u_mask_p, u_sel, u_neibs, b1, lane, iu1, wu1, au1_);
    load_meta<int>(v_mask_p, v_sel, v_neibs, b1, lane, iv1, wv1, av1_);
  } else if (lay == 1) {
    load_meta<unsigned char>(u_mask_p, u_sel, u_neibs, b0, lane, iu0, wu0, au0_);
    load_meta<unsigned char>(v_mask_p, v_sel, v_neibs, b0, lane, iv0, wv0, av0_);
    load_meta<unsigned char>(u_mask_p, u_sel, u_neibs, b1, lane, iu1, wu1, au1_);
    load_meta<unsigned char>(v_mask_p, v_sel, v_neibs, b1, lane, iv1, wv1, av1_);
  } else {
    load_meta<float>(u_mask_p, u_sel, u_neibs, b0, lane, iu0, wu0, au0_);
    load_meta<float>(v_mask_p, v_sel, v_neibs, b0, lane, iv0, wv0, av0_);
    load_meta<float>(u_mask_p, u_sel, u_neibs, b1, lane, iu1, wu1, au1_);
    load_meta<float>(v_mask_p, v_sel, v_neibs, b1, lane, iv1, wv1, av1_);
  }
  const int cnt_u0 = compact_side(lane, iu0, wu0, au0_, sidx[e0][0], swt[e0][0]);
  const int cnt_v0 = compact_side(lane, iv0, wv0, av0_, sidx[e0][1], swt[e0][1]);
  const int cnt_u1 = compact_side(lane, iu1, wu1, au1_, sidx[e1][0], swt[e1][0]);
  const int cnt_v1 = compact_side(lane, iv1, wv1, av1_, sidx[e1][1], swt[e1][1]);

  // ---- Phase 1b: two-bank ping-pong gather pipeline ------------------------
  float accu0 = 0.f, accv0 = 0.f, accu1 = 0.f, accv1 = 0.f;
  {
    const int*   __restrict__ pI0 = sidx[e0][0];
    const float* __restrict__ pW0 = swt [e0][0];
    const int*   __restrict__ pI1 = sidx[e0][1];
    const float* __restrict__ pW1 = swt [e0][1];
    const int*   __restrict__ pI2 = sidx[e1][0];
    const float* __restrict__ pW2 = swt [e1][0];
    const int*   __restrict__ pI3 = sidx[e1][1];
    const float* __restrict__ pW3 = swt [e1][1];

    float r0[8], r1[8], r2[8], r3[8];   // 2 banks x 4 slots per stream

#define ISSUE_BANK(S, B) do { _Pragma("unroll")                              \
    for (int j = 0; j < 4; ++j) {                                            \
      r0[(B)*4 + j] = u2e[(size_t)pI0[(S) + j] * DIM + lane];                \
      r1[(B)*4 + j] = v2e[(size_t)pI1[(S) + j] * DIM + lane];                \
      r2[(B)*4 + j] = u2e[(size_t)pI2[(S) + j] * DIM + lane];                \
      r3[(B)*4 + j] = v2e[(size_t)pI3[(S) + j] * DIM + lane];                \
    } } while (0)

#define FMA_BANK(S, B) do { _Pragma("unroll")                                \
    for (int j = 0; j < 4; ++j) {                                            \
      accu0 = fmaf(pW0[(S) + j], r0[(B)*4 + j], accu0);                      \
      accv0 = fmaf(pW1[(S) + j], r1[(B)*4 + j], accv0);                      \
      accu1 = fmaf(pW2[(S) + j], r2[(B)*4 + j], accu1);                      \
      accv1 = fmaf(pW3[(S) + j], r3[(B)*4 + j], accv1);                      \
    } } while (0)

    int cmax = max(max(cnt_u0, cnt_v0), max(cnt_u1, cnt_v1));
    int cm8  = (cmax + 7) & ~7;         // tail slots hold (0, 0.0f)
    if (cm8 < 8) cm8 = 8;               // cm8 in [8, 56]

    ISSUE_BANK(0, 0);                   // 16 loads outstanding
    ISSUE_BANK(4, 1);                   // 32 outstanding
    int s = 0;
    for (; s + 8 < cm8; s += 8) {
      FMA_BANK(s, 0);     ISSUE_BANK(s + 8, 0);    // wait only bank-0's 16
      FMA_BANK(s + 4, 1); ISSUE_BANK(s + 12, 1);   // refill to 32 in flight
    }
    FMA_BANK(s, 0);
    FMA_BANK(s + 4, 1);
#undef ISSUE_BANK
#undef FMA_BANK
  }

  // ---- stage concat vectors (all 64 lanes, no cross-lane reduce needed) ----
  sx[e0][lane]       = self_u0;
  sx[e0][ 64 + lane] = accu0 * (1.0f / fmaxf((float)cnt_u0, 1.0f));
  sx[e0][128 + lane] = self_v0;
  sx[e0][192 + lane] = accv0 * (1.0f / fmaxf((float)cnt_v0, 1.0f));
  sx[e1][lane]       = self_u1;
  sx[e1][ 64 + lane] = accu1 * (1.0f / fmaxf((float)cnt_u1, 1.0f));
  sx[e1][128 + lane] = self_v1;
  sx[e1][192 + lane] = accv1 * (1.0f / fmaxf((float)cnt_v1, 1.0f));
  __syncthreads();

  // ---- Phase 2: mat-vec mini-GEMM ------------------------------------------
  // wave = (side, 4 elements), lane = output dim, k = 0..127
  {
    const int side = wvid & 1;
    const int eb   = (wvid >> 1) * 4;
    const float* __restrict__ W = side ? Wv : Wu;
    const float  bias = side ? bv[lane] : bu[lane];
    float a0 = bias, a1 = bias, a2 = bias, a3 = bias;
    const int xoff = side * 128;

    #pragma unroll 2
    for (int k4 = 0; k4 < 32; ++k4) {
      const int k = k4 * 4;
      float w0 = W[(k + 0) * DIM + lane];
      float w1 = W[(k + 1) * DIM + lane];
      float w2 = W[(k + 2) * DIM + lane];
      float w3 = W[(k + 3) * DIM + lane];
      float4 x0 = *(const float4*)&sx[eb + 0][xoff + k];
      float4 x1 = *(const float4*)&sx[eb + 1][xoff + k];
      float4 x2 = *(const float4*)&sx[eb + 2][xoff + k];
      float4 x3 = *(const float4*)&sx[eb + 3][xoff + k];
      a0 = fmaf(x0.x, w0, a0); a0 = fmaf(x0.y, w1, a0);
      a0 = fmaf(x0.z, w2, a0); a0 = fmaf(x0.w, w3, a0);
      a1 = fmaf(x1.x, w0, a1); a1 = fmaf(x1.y, w1, a1);
      a1 = fmaf(x1.z, w2, a1); a1 = fmaf(x1.w, w3, a1);
      a2 = fmaf(x2.x, w0, a2); a2 = fmaf(x2.y, w1, a2);
      a2 = fmaf(x2.z, w2, a2); a2 = fmaf(x2.w, w3, a2);
      a3 = fmaf(x3.x, w0, a3); a3 = fmaf(x3.y, w1, a3);
      a3 = fmaf(x3.z, w2, a3); a3 = fmaf(x3.w, w3, a3);
    }
    slin[side][eb + 0][lane] = a0;
    slin[side][eb + 1][lane] = a1;
    slin[side][eb + 2][lane] = a2;
    slin[side][eb + 3][lane] = a3;
  }
  __syncthreads();

  // ---- Phase 3: select + dot (counts still in registers) -------------------
  {
    float ue = (cnt_u0 > 0) ? slin[0][e0][lane] : sx[e0][lane];
    float ve = (cnt_v0 > 0) ? slin[1][e0][lane] : sx[e0][128 + lane];
    float p = ue * ve;
    #pragma unroll
    for (int off = 32; off > 0; off >>= 1) p += __shfl_xor(p, off, 64);
    if (lane == 0) out[g0] = p;
  }
  {
    float ue = (cnt_u1 > 0) ? slin[0][e1][lane] : sx[e1][lane];
    float ve = (cnt_v1 > 0) ? slin[1][e1][lane] : sx[e1][128 + lane];
    float p = ue * ve;
    #pragma unroll
    for (int off = 32; off > 0; off >>= 1) p += __shfl_xor(p, off, 64);
    if (lane == 0) out[g1] = p;
  }
}

extern "C" void kernel_launch(void* const* d_in, const int* in_sizes, int n_in,
                              void* d_out, int out_size, void* d_ws, size_t ws_size,
                              hipStream_t stream) {
  const int*   nodes_u = (const int*)  d_in[0];
  const int*   nodes_v = (const int*)  d_in[1];
  const int*   u_neibs = (const int*)  d_in[2];
  const int*   v_neibs = (const int*)  d_in[3];
  const void*  u_mask  =               d_in[4];
  const void*  v_mask  =               d_in[5];
  const float* u_sel   = (const float*)d_in[6];
  const float* v_sel   = (const float*)d_in[7];
  const float* u2e     = (const float*)d_in[8];
  const float* v2e     = (const float*)d_in[9];
  const float* Wu      = (const float*)d_in[10];
  const float* bu      = (const float*)d_in[11];
  const float* Wv      = (const float*)d_in[12];
  const float* bv      = (const float*)d_in[13];
  float* out = (float*)d_out;

  const int batch = in_sizes[0];           // 16384
  fused_graphsage_dot<<<batch / EPB, 512, 0, stream>>>(
      nodes_u, nodes_v, u_neibs, v_neibs, u_mask, v_mask, u_sel, v_sel,
      u2e, v2e, Wu, bu, Wv, bv, out);
}

// Round 8
// 48.663 us; speedup vs baseline: 2.0268x; 2.0268x over previous
//
#include <hip/hip_runtime.h>

// Fused two-sided GraphSage-style embed + linear + dot. Single kernel.
// B=16384, MAX_DEG=50, D=64. Block = 512 threads (8 waves), EPB=16 elems,
// grid = 1024.
// R8 = R6 with __launch_bounds__(512,4): lift the 64-VGPR cap (which pinned
// the allocator at 32 regs + scratch-spill in R3-R7) in exchange for
// 16 waves/CU occupancy. Everything else identical to R6.
// Phase 0: in-kernel mask-layout detection (wave 0, ballots).
// Phase 1: lane = embedding dim. Metadata for both elems -> SoA compaction
//          (idx,w) into LDS -> interleaved scalar-row gathers over all
//          4 (elem,side) streams, scalar per-lane accumulators.
// Phase 2: mat-vec mini-GEMM, wave = (side, 4 elems), W amortized, unroll 2.
// Phase 3: select + dot + wave reduce.

constexpr int KDEG  = 50;
constexpr int DIM   = 64;
constexpr int SLOTS = 56;             // KDEG padded to multiple of 8
constexpr int EPB   = 16;             // elements per block

template <typename MT>
__device__ __forceinline__ void load_meta(const void* __restrict__ mask_p,
                                          const float* __restrict__ sel,
                                          const int* __restrict__ neibs,
                                          int base, int lane,
                                          int& idx, float& w, bool& act) {
  if (lane < KDEG) {
    MT m    = ((const MT*)mask_p)[base + lane];
    float s = sel[base + lane];
    idx     = neibs[base + lane];
    act     = (m != (MT)0);
    w       = act ? s : 0.0f;
  } else { idx = 0; w = 0.0f; act = false; }
}

// Compact active (idx,w) into slots [0,cnt); fill [cnt,SLOTS) with zeros. SoA.
__device__ __forceinline__ int compact_side(int lane, int idx, float w, bool act,
                                            int* __restrict__ sidx,
                                            float* __restrict__ sw) {
  unsigned long long balA = __ballot(act);
  unsigned long long balI = __ballot(!act && (lane < SLOTS));
  int cnt = __popcll(balA);
  unsigned long long below = (1ULL << lane) - 1ULL;
  int pos = act ? __popcll(balA & below)
                : cnt + __popcll(balI & below);
  if (lane < SLOTS) {
    sidx[pos] = act ? idx : 0;
    sw[pos]   = act ? w   : 0.0f;
  }
  return cnt;
}

__global__ __launch_bounds__(512, 4) void fused_graphsage_dot(
    const int* __restrict__ nodes_u, const int* __restrict__ nodes_v,
    const int* __restrict__ u_neibs, const int* __restrict__ v_neibs,
    const void* __restrict__ u_mask_p, const void* __restrict__ v_mask_p,
    const float* __restrict__ u_sel, const float* __restrict__ v_sel,
    const float* __restrict__ u2e, const float* __restrict__ v2e,
    const float* __restrict__ Wu, const float* __restrict__ bu,
    const float* __restrict__ Wv, const float* __restrict__ bv,
    float* __restrict__ out)
{
  __shared__ float sx  [EPB][256];      // [self_u|agg_u|self_v|agg_v] per elem
  __shared__ float slin[2][EPB][DIM];   // mat-vec results per side
  __shared__ int   sidx[EPB][2][SLOTS];
  __shared__ float swt [EPB][2][SLOTS];
  __shared__ int   slay;

  const int lane = threadIdx.x & 63;    // = embedding dim in phase 1
  const int wvid = threadIdx.x >> 6;    // 0..7
  const int eb0  = blockIdx.x * EPB;
  const int e0   = wvid * 2, e1 = e0 + 1;
  const int g0   = eb0 + e0, g1 = eb0 + e1;
  const int b0   = g0 * KDEG, b1 = g1 * KDEG;

  // self-embedding loads issued first (independent of everything below)
  float self_u0 = u2e[(size_t)nodes_u[g0] * DIM + lane];
  float self_v0 = v2e[(size_t)nodes_v[g0] * DIM + lane];
  float self_u1 = u2e[(size_t)nodes_u[g1] * DIM + lane];
  float self_v1 = v2e[(size_t)nodes_v[g1] * DIM + lane];

  // ---- Phase 0: mask storage layout detection (bool dtype ambiguity) ------
  // lay 0: int32 0/1   lay 1: uint8 0/1   lay 2: float32 0.0/1.0
  if (wvid == 0) {
    uchar4 b4 = ((const uchar4*)u_mask_p)[lane];   // first 256 bytes
    bool gt1  = (b4.x > 1) | (b4.y > 1) | (b4.z > 1) | (b4.w > 1);
    bool offw = ((b4.y | b4.z | b4.w) != 0);
    unsigned long long bg = __ballot(gt1);
    unsigned long long bo = __ballot(offw);
    if (lane == 0) slay = bg ? 2 : (bo ? 1 : 0);
  }
  __syncthreads();
  const int lay = slay;

  // ---- Phase 1a: metadata for BOTH elements, then SoA compaction -----------
  int iu0, iv0, iu1, iv1; float wu0, wv0, wu1, wv1; bool au0_, av0_, au1_, av1_;
  if (lay == 0) {
    load_meta<int>(u_mask_p, u_sel, u_neibs, b0, lane, iu0, wu0, au0_);
    load_meta<int>(v_mask_p, v_sel, v_neibs, b0, lane, iv0, wv0, av0_);
    load_meta<int>(u_mask_p, u_sel, u_neibs, b1, lane, iu1, wu1, au1_);
    load_meta<int>(v_mask_p, v_sel, v_neibs, b1, lane, iv1, wv1, av1_);
  } else if (lay == 1) {
    load_meta<unsigned char>(u_mask_p, u_sel, u_neibs, b0, lane, iu0, wu0, au0_);
    load_meta<unsigned char>(v_mask_p, v_sel, v_neibs, b0, lane, iv0, wv0, av0_);
    load_meta<unsigned char>(u_mask_p, u_sel, u_neibs, b1, lane, iu1, wu1, au1_);
    load_meta<unsigned char>(v_mask_p, v_sel, v_neibs, b1, lane, iv1, wv1, av1_);
  } else {
    load_meta<float>(u_mask_p, u_sel, u_neibs, b0, lane, iu0, wu0, au0_);
    load_meta<float>(v_mask_p, v_sel, v_neibs, b0, lane, iv0, wv0, av0_);
    load_meta<float>(u_mask_p, u_sel, u_neibs, b1, lane, iu1, wu1, au1_);
    load_meta<float>(v_mask_p, v_sel, v_neibs, b1, lane, iv1, wv1, av1_);
  }
  const int cnt_u0 = compact_side(lane, iu0, wu0, au0_, sidx[e0][0], swt[e0][0]);
  const int cnt_v0 = compact_side(lane, iv0, wv0, av0_, sidx[e0][1], swt[e0][1]);
  const int cnt_u1 = compact_side(lane, iu1, wu1, au1_, sidx[e1][0], swt[e1][0]);
  const int cnt_v1 = compact_side(lane, iv1, wv1, av1_, sidx[e1][1], swt[e1][1]);

  // ---- Phase 1b: interleaved scalar-row gathers (4 streams) ----------------
  float accu0 = 0.f, accv0 = 0.f, accu1 = 0.f, accv1 = 0.f;
  {
    const int*   __restrict__ pI0 = sidx[e0][0];
    const float* __restrict__ pW0 = swt [e0][0];
    const int*   __restrict__ pI1 = sidx[e0][1];
    const float* __restrict__ pW1 = swt [e0][1];
    const int*   __restrict__ pI2 = sidx[e1][0];
    const float* __restrict__ pW2 = swt [e1][0];
    const int*   __restrict__ pI3 = sidx[e1][1];
    const float* __restrict__ pW3 = swt [e1][1];

    int cmax = max(max(cnt_u0, cnt_v0), max(cnt_u1, cnt_v1));
    int cm4  = (cmax + 3) & ~3;         // tail slots hold (0, 0.0f)
    for (int s = 0; s < cm4; s += 4) {
      #pragma unroll
      for (int j = 0; j < 4; ++j) {
        const int t = s + j;
        accu0 = fmaf(pW0[t], u2e[(size_t)pI0[t] * DIM + lane], accu0);
        accv0 = fmaf(pW1[t], v2e[(size_t)pI1[t] * DIM + lane], accv0);
        accu1 = fmaf(pW2[t], u2e[(size_t)pI2[t] * DIM + lane], accu1);
        accv1 = fmaf(pW3[t], v2e[(size_t)pI3[t] * DIM + lane], accv1);
      }
    }
  }

  // ---- stage concat vectors (all 64 lanes, no cross-lane reduce needed) ----
  sx[e0][lane]       = self_u0;
  sx[e0][ 64 + lane] = accu0 * (1.0f / fmaxf((float)cnt_u0, 1.0f));
  sx[e0][128 + lane] = self_v0;
  sx[e0][192 + lane] = accv0 * (1.0f / fmaxf((float)cnt_v0, 1.0f));
  sx[e1][lane]       = self_u1;
  sx[e1][ 64 + lane] = accu1 * (1.0f / fmaxf((float)cnt_u1, 1.0f));
  sx[e1][128 + lane] = self_v1;
  sx[e1][192 + lane] = accv1 * (1.0f / fmaxf((float)cnt_v1, 1.0f));
  __syncthreads();

  // ---- Phase 2: mat-vec mini-GEMM ------------------------------------------
  // wave = (side, 4 elements), lane = output dim, k = 0..127
  {
    const int side = wvid & 1;
    const int eb   = (wvid >> 1) * 4;
    const float* __restrict__ W = side ? Wv : Wu;
    const float  bias = side ? bv[lane] : bu[lane];
    float a0 = bias, a1 = bias, a2 = bias, a3 = bias;
    const int xoff = side * 128;

    #pragma unroll 2
    for (int k4 = 0; k4 < 32; ++k4) {
      const int k = k4 * 4;
      float w0 = W[(k + 0) * DIM + lane];
      float w1 = W[(k + 1) * DIM + lane];
      float w2 = W[(k + 2) * DIM + lane];
      float w3 = W[(k + 3) * DIM + lane];
      float4 x0 = *(const float4*)&sx[eb + 0][xoff + k];
      float4 x1 = *(const float4*)&sx[eb + 1][xoff + k];
      float4 x2 = *(const float4*)&sx[eb + 2][xoff + k];
      float4 x3 = *(const float4*)&sx[eb + 3][xoff + k];
      a0 = fmaf(x0.x, w0, a0); a0 = fmaf(x0.y, w1, a0);
      a0 = fmaf(x0.z, w2, a0); a0 = fmaf(x0.w, w3, a0);
      a1 = fmaf(x1.x, w0, a1); a1 = fmaf(x1.y, w1, a1);
      a1 = fmaf(x1.z, w2, a1); a1 = fmaf(x1.w, w3, a1);
      a2 = fmaf(x2.x, w0, a2); a2 = fmaf(x2.y, w1, a2);
      a2 = fmaf(x2.z, w2, a2); a2 = fmaf(x2.w, w3, a2);
      a3 = fmaf(x3.x, w0, a3); a3 = fmaf(x3.y, w1, a3);
      a3 = fmaf(x3.z, w2, a3); a3 = fmaf(x3.w, w3, a3);
    }
    slin[side][eb + 0][lane] = a0;
    slin[side][eb + 1][lane] = a1;
    slin[side][eb + 2][lane] = a2;
    slin[side][eb + 3][lane] = a3;
  }
  __syncthreads();

  // ---- Phase 3: select + dot (counts still in registers) -------------------
  {
    float ue = (cnt_u0 > 0) ? slin[0][e0][lane] : sx[e0][lane];
    float ve = (cnt_v0 > 0) ? slin[1][e0][lane] : sx[e0][128 + lane];
    float p = ue * ve;
    #pragma unroll
    for (int off = 32; off > 0; off >>= 1) p += __shfl_xor(p, off, 64);
    if (lane == 0) out[g0] = p;
  }
  {
    float ue = (cnt_u1 > 0) ? slin[0][e1][lane] : sx[e1][lane];
    float ve = (cnt_v1 > 0) ? slin[1][e1][lane] : sx[e1][128 + lane];
    float p = ue * ve;
    #pragma unroll
    for (int off = 32; off > 0; off >>= 1) p += __shfl_xor(p, off, 64);
    if (lane == 0) out[g1] = p;
  }
}

extern "C" void kernel_launch(void* const* d_in, const int* in_sizes, int n_in,
                              void* d_out, int out_size, void* d_ws, size_t ws_size,
                              hipStream_t stream) {
  const int*   nodes_u = (const int*)  d_in[0];
  const int*   nodes_v = (const int*)  d_in[1];
  const int*   u_neibs = (const int*)  d_in[2];
  const int*   v_neibs = (const int*)  d_in[3];
  const void*  u_mask  =               d_in[4];
  const void*  v_mask  =               d_in[5];
  const float* u_sel   = (const float*)d_in[6];
  const float* v_sel   = (const float*)d_in[7];
  const float* u2e     = (const float*)d_in[8];
  const float* v2e     = (const float*)d_in[9];
  const float* Wu      = (const float*)d_in[10];
  const float* bu      = (const float*)d_in[11];
  const float* Wv      = (const float*)d_in[12];
  const float* bv      = (const float*)d_in[13];
  float* out = (float*)d_out;

  const int batch = in_sizes[0];           // 16384
  fused_graphsage_dot<<<batch / EPB, 512, 0, stream>>>(
      nodes_u, nodes_v, u_neibs, v_neibs, u_mask, v_mask, u_sel, v_sel,
      u2e, v2e, Wu, bu, Wv, bv, out);
}